// Round 3
// baseline (562.767 us; speedup 1.0000x reference)
//
#include <hip/hip_runtime.h>
#include <math.h>

#define NE 8
#define HD 2048
#define ID 1408
#define NT 512
#define NENT 1024
#define FP8MAX 448.0f

typedef __attribute__((ext_vector_type(4))) float floatx4;

__device__ __forceinline__ floatx4 fzero4() {
    floatx4 z; z.x = 0.f; z.y = 0.f; z.z = 0.f; z.w = 0.f; return z;
}

// ---- ws layout (bytes), all 256-aligned ----
#define OFF_OFFS  0                         // int[16]
#define OFF_TOK   1024                      // int[1024]
#define OFF_WGT   8192                      // float[1024]
#define OFF_XS    16384                     // float[512*16]
#define OFF_XQ    65536                     // u8[512*2048]  (1 MiB)
#define OFF_HS    (2*1024*1024)             // float[1024*11]
#define OFF_HQ    (2*1024*1024 + 65536)     // u8[1024*1408]
#define OFF_H32   (4*1024*1024)             // float[1024*1408] (5.77 MB)
#define OFF_WGU8  (10*1024*1024)            // u8[8*2816*2048] = 46.14 MB
#define OFF_WD8   (OFF_WGU8 + 46137344)     // u8[8*2048*1408] = 23.07 MB
#define WS_NEED   ((size_t)OFF_WD8 + 23068672)

#define LDA 136   // LDS row pitch for 128-byte fp8 rows

// ---------------- routing: build per-expert compact entry lists ----------------
__global__ void route_kernel(const int* __restrict__ tki,
                             const float* __restrict__ tkw,
                             int* __restrict__ offs,
                             int* __restrict__ tok,
                             float* __restrict__ wgt) {
    __shared__ int cnt[NE];
    __shared__ int cur[NE];
    __shared__ int base[NE + 1];
    int tid = threadIdx.x;               // 1024 threads, one per (token, slot)
    if (tid < NE) { cnt[tid] = 0; cur[tid] = 0; }
    __syncthreads();
    int e = tki[tid];
    atomicAdd(&cnt[e], 1);
    __syncthreads();
    if (tid == 0) {
        int s = 0;
        for (int i = 0; i < NE; i++) { base[i] = s; s += cnt[i]; }
        base[NE] = s;
    }
    __syncthreads();
    int pos = atomicAdd(&cur[e], 1);
    int j = base[e] + pos;
    tok[j] = tid >> 1;                   // token id
    wgt[j] = tkw[tid];
    if (tid <= NE) offs[tid] = base[tid];
}

// ---------------- streaming weight conversion fp32 -> fp8 --------------------
__global__ __launch_bounds__(256) void conv_w_kernel(
    const float* __restrict__ wgu, const float* __restrict__ wd,
    unsigned char* __restrict__ wgu8, unsigned char* __restrict__ wd8) {
    const long N1 = 11534336;   // wgu float4 count (8*2816*2048/4)
    const long N2 = 5767168;    // wd  float4 count (8*2048*1408/4)
    long stride = (long)gridDim.x * 256;
    for (long i = (long)blockIdx.x * 256 + threadIdx.x; i < N1 + N2; i += stride) {
        const float4* src;
        unsigned char* dst;
        long j;
        if (i < N1) { src = (const float4*)wgu; dst = wgu8; j = i; }
        else        { src = (const float4*)wd;  dst = wd8;  j = i - N1; }
        float4 f = src[j];
        int p = __builtin_amdgcn_cvt_pk_fp8_f32(f.x, f.y, 0, false);
        p = __builtin_amdgcn_cvt_pk_fp8_f32(f.z, f.w, p, true);
        *(unsigned int*)(dst + j * 4) = (unsigned int)p;
    }
}

// ---------------- activation quantization: wave per (token, 128-block) --------
__global__ void quant_x_kernel(const float* __restrict__ x,
                               unsigned char* __restrict__ xq,
                               float* __restrict__ xs) {
    int wid = (blockIdx.x * 256 + threadIdx.x) >> 6;   // 0..8191
    int lane = threadIdx.x & 63;
    int t = wid >> 4;
    int b = wid & 15;
    const float2 v = *(const float2*)(x + (long)t * HD + b * 128 + lane * 2);
    float am = fmaxf(fabsf(v.x), fabsf(v.y));
    #pragma unroll
    for (int m = 32; m; m >>= 1) am = fmaxf(am, __shfl_xor(am, m));
    float scale = fmaxf(am, 1e-12f) / FP8MAX;
    int p = __builtin_amdgcn_cvt_pk_fp8_f32(v.x / scale, v.y / scale, 0, false);
    *(unsigned short*)(xq + (long)t * HD + b * 128 + lane * 2) =
        (unsigned short)(p & 0xffff);
    if (lane == 0) xs[t * 16 + b] = scale;
}

// ---------------- h quantization: wave per (entry, 128-block of 11) ----------
__global__ void quant_h_kernel(const float* __restrict__ h32,
                               unsigned char* __restrict__ hq,
                               float* __restrict__ hs) {
    int wid = (blockIdx.x * 256 + threadIdx.x) >> 6;   // 0..11263
    int lane = threadIdx.x & 63;
    int j = wid / 11;
    int b = wid - j * 11;
    const float2 v = *(const float2*)(h32 + (long)j * ID + b * 128 + lane * 2);
    float am = fmaxf(fabsf(v.x), fabsf(v.y));
    #pragma unroll
    for (int m = 32; m; m >>= 1) am = fmaxf(am, __shfl_xor(am, m));
    float scale = fmaxf(am, 1e-12f) / FP8MAX;
    int p = __builtin_amdgcn_cvt_pk_fp8_f32(v.x / scale, v.y / scale, 0, false);
    *(unsigned short*)(hq + (long)j * ID + b * 128 + lane * 2) =
        (unsigned short)(p & 0xffff);
    if (lane == 0) hs[j * 11 + b] = scale;
}

// ---------------- gemm1: BM=256 entries x BN=32 gate/up col pairs ------------
// WFP8=1: weights pre-converted to fp8 (wguv -> u8). WFP8=0: inline convert.
template<int WFP8>
__global__ __launch_bounds__(256) void gemm1_kernel(
    const unsigned char* __restrict__ xq,
    const float* __restrict__ xs,
    const void* __restrict__ wguv,
    const float* __restrict__ sgu,   // [E][22][16]
    const int* __restrict__ offs,
    const int* __restrict__ tok,
    float* __restrict__ h32) {
    int e = blockIdx.z;
    int mt = blockIdx.y;
    int jb = blockIdx.x;             // 0..43 (32-col gate/up pair tiles)
    int o0 = offs[e], o1 = offs[e + 1];
    int ne = o1 - o0;
    int m0 = mt * 256;
    if (m0 >= ne) return;
    int rem = ne - m0;

    __shared__ __align__(16) unsigned char Asm[256 * LDA];  // 34816
    __shared__ __align__(16) unsigned char Bsm[64 * LDA];   // 8704
    __shared__ float sxa[256 * 16];                         // 16384
    __shared__ int tokL[256];

    int tid = threadIdx.x;
    {
        int j = o0 + m0 + tid;
        if (j >= o1) j = o0;           // pad rows: duplicate a valid entry
        tokL[tid] = tok[j];
    }
    __syncthreads();
    {   // stage per-row x scales for all 16 k-blocks
        const float4* s = (const float4*)(xs + tokL[tid] * 16);
        float4 a0 = s[0], a1 = s[1], a2 = s[2], a3 = s[3];
        float4* d = (float4*)(sxa + tid * 16);
        d[0] = a0; d[1] = a1; d[2] = a2; d[3] = a3;
    }

    int wave = tid >> 6;
    int lane = tid & 63;
    int lr = lane & 15;
    int lq = lane >> 4;

    const unsigned char* aptr = xq + (long)tokL[tid] * HD;
    int br = tid >> 2, bq = tid & 3;         // B: 64 rows, 32-elem quarters
    long bn = (br < 32) ? (long)(jb * 32 + br)
                        : (long)(1408 + jb * 32 + (br - 32));
    const unsigned char* bptr8 = WFP8 ? (const unsigned char*)wguv + ((long)e * 2816 + bn) * 2048 : nullptr;
    const float* bptrf = WFP8 ? nullptr : (const float*)wguv + ((long)e * 2816 + bn) * 2048;
    const float* sgp = sgu + (e * 22 + (jb >> 2)) * 16;
    const float* sup = sgu + (e * 22 + 11 + (jb >> 2)) * 16;

    floatx4 facc[16];
    #pragma unroll
    for (int i = 0; i < 16; i++) facc[i] = fzero4();

    uint4 aP[8];
    uint4 bP8[2];
    float4 bPf[8];

    auto loadAB = [&](int kb) {
        const uint4* asrc = (const uint4*)(aptr + kb * 128);
        #pragma unroll
        for (int i = 0; i < 8; i++) aP[i] = asrc[i];
        if (WFP8) {
            const uint4* bsrc = (const uint4*)(bptr8 + kb * 128 + bq * 32);
            bP8[0] = bsrc[0];
            bP8[1] = bsrc[1];
        } else {
            const float4* bsrc = (const float4*)(bptrf + kb * 128 + bq * 32);
            #pragma unroll
            for (int g = 0; g < 8; g++) bPf[g] = bsrc[g];
        }
    };
    loadAB(0);

    for (int kb = 0; kb < 16; kb++) {
        #pragma unroll
        for (int i = 0; i < 8; i++)
            *(uint4*)(&Asm[tid * LDA + i * 16]) = aP[i];
        if (WFP8) {
            *(uint4*)(&Bsm[br * LDA + bq * 32]) = bP8[0];
            *(uint4*)(&Bsm[br * LDA + bq * 32 + 16]) = bP8[1];
        } else {
            unsigned int pk[8];
            #pragma unroll
            for (int g = 0; g < 8; g++) {
                float4 f = bPf[g];
                int p = __builtin_amdgcn_cvt_pk_fp8_f32(f.x, f.y, 0, false);
                p = __builtin_amdgcn_cvt_pk_fp8_f32(f.z, f.w, p, true);
                pk[g] = (unsigned int)p;
            }
            *(uint4*)(&Bsm[br * LDA + bq * 32]) =
                make_uint4(pk[0], pk[1], pk[2], pk[3]);
            *(uint4*)(&Bsm[br * LDA + bq * 32 + 16]) =
                make_uint4(pk[4], pk[5], pk[6], pk[7]);
        }
        __syncthreads();
        if (kb < 15) loadAB(kb + 1);   // overlap next fetch with MFMA phase
        floatx4 cacc[16];
        #pragma unroll
        for (int i = 0; i < 16; i++) cacc[i] = fzero4();
        #pragma unroll
        for (int ks = 0; ks < 4; ks++) {
            long a[4], b[4];
            #pragma unroll
            for (int mi = 0; mi < 4; mi++)
                a[mi] = *(const long*)(&Asm[(wave * 64 + mi * 16 + lr) * LDA + ks * 32 + lq * 8]);
            #pragma unroll
            for (int ni = 0; ni < 4; ni++)
                b[ni] = *(const long*)(&Bsm[(ni * 16 + lr) * LDA + ks * 32 + lq * 8]);
            #pragma unroll
            for (int mi = 0; mi < 4; mi++)
                #pragma unroll
                for (int ni = 0; ni < 4; ni++)
                    cacc[mi * 4 + ni] = __builtin_amdgcn_mfma_f32_16x16x32_fp8_fp8(
                        a[mi], b[ni], cacc[mi * 4 + ni], 0, 0, 0);
        }
        float sg = sgp[kb];
        float su = sup[kb];
        #pragma unroll
        for (int mi = 0; mi < 4; mi++) {
            #pragma unroll
            for (int reg = 0; reg < 4; reg++) {
                float sx = sxa[(wave * 64 + mi * 16 + lq * 4 + reg) * 16 + kb];
                #pragma unroll
                for (int ni = 0; ni < 4; ni++) {
                    float sw = (ni < 2) ? sg : su;
                    facc[mi * 4 + ni][reg] += cacc[mi * 4 + ni][reg] * (sw * sx);
                }
            }
        }
        __syncthreads();
    }

    // epilogue: h = silu(gate) * up   (ni 0,1 = gate; ni 2,3 = matching up)
    #pragma unroll
    for (int mi = 0; mi < 4; mi++) {
        #pragma unroll
        for (int ni = 0; ni < 2; ni++) {
            #pragma unroll
            for (int reg = 0; reg < 4; reg++) {
                int r = wave * 64 + mi * 16 + lq * 4 + reg;
                if (r < rem) {
                    float g = facc[mi * 4 + ni][reg];
                    float u = facc[mi * 4 + ni + 2][reg];
                    float hval = (g / (1.0f + expf(-g))) * u;
                    h32[(long)(o0 + m0 + r) * ID + jb * 32 + ni * 16 + lr] = hval;
                }
            }
        }
    }
}

// ---------------- gemm2: BM=256 entries x BN=64 H-cols, weighted scatter -----
template<int WFP8>
__global__ __launch_bounds__(256) void gemm2_kernel(
    const unsigned char* __restrict__ hq,
    const float* __restrict__ hs,
    const void* __restrict__ wdv,
    const float* __restrict__ sd,    // [E][16][11]
    const int* __restrict__ offs,
    const int* __restrict__ tok,
    const float* __restrict__ wgt,
    float* __restrict__ out) {
    int e = blockIdx.z;
    int mt = blockIdx.y;
    int jb = blockIdx.x;             // 0..31 (64 H-cols each)
    int o0 = offs[e], o1 = offs[e + 1];
    int ne = o1 - o0;
    int m0 = mt * 256;
    if (m0 >= ne) return;
    int rem = ne - m0;

    __shared__ __align__(16) unsigned char Asm[256 * LDA];  // 34816
    __shared__ __align__(16) unsigned char Bsm[64 * LDA];   // 8704
    __shared__ float sha[256 * 12];                         // 12288
    __shared__ int tokL[256];
    __shared__ float wgtL[256];

    int tid = threadIdx.x;
    int jent;
    {
        int j = o0 + m0 + tid;
        int valid = j < o1;
        if (!valid) j = o0;
        jent = j;
        tokL[tid] = tok[j];
        wgtL[tid] = valid ? wgt[j] : 0.0f;
    }
    {   // per-row h scales (11 k-blocks)
        const float* s = hs + jent * 11;
        #pragma unroll
        for (int k = 0; k < 11; k++) sha[tid * 12 + k] = s[k];
    }

    int wave = tid >> 6;
    int lane = tid & 63;
    int lr = lane & 15;
    int lq = lane >> 4;

    const unsigned char* aptr = hq + (long)jent * ID;
    int br = tid >> 2, bq = tid & 3;
    const unsigned char* bptr8 = WFP8 ? (const unsigned char*)wdv + ((long)e * 2048 + jb * 64 + br) * 1408 : nullptr;
    const float* bptrf = WFP8 ? nullptr : (const float*)wdv + ((long)e * 2048 + jb * 64 + br) * 1408;
    const float* sdp = sd + (e * 16 + (jb >> 1)) * 11;

    floatx4 facc[16];
    #pragma unroll
    for (int i = 0; i < 16; i++) facc[i] = fzero4();

    uint4 aP[8];
    uint4 bP8[2];
    float4 bPf[8];

    auto loadAB = [&](int kb) {
        const uint4* asrc = (const uint4*)(aptr + kb * 128);
        #pragma unroll
        for (int i = 0; i < 8; i++) aP[i] = asrc[i];
        if (WFP8) {
            const uint4* bsrc = (const uint4*)(bptr8 + kb * 128 + bq * 32);
            bP8[0] = bsrc[0];
            bP8[1] = bsrc[1];
        } else {
            const float4* bsrc = (const float4*)(bptrf + kb * 128 + bq * 32);
            #pragma unroll
            for (int g = 0; g < 8; g++) bPf[g] = bsrc[g];
        }
    };
    loadAB(0);

    for (int kb = 0; kb < 11; kb++) {
        #pragma unroll
        for (int i = 0; i < 8; i++)
            *(uint4*)(&Asm[tid * LDA + i * 16]) = aP[i];
        if (WFP8) {
            *(uint4*)(&Bsm[br * LDA + bq * 32]) = bP8[0];
            *(uint4*)(&Bsm[br * LDA + bq * 32 + 16]) = bP8[1];
        } else {
            unsigned int pk[8];
            #pragma unroll
            for (int g = 0; g < 8; g++) {
                float4 f = bPf[g];
                int p = __builtin_amdgcn_cvt_pk_fp8_f32(f.x, f.y, 0, false);
                p = __builtin_amdgcn_cvt_pk_fp8_f32(f.z, f.w, p, true);
                pk[g] = (unsigned int)p;
            }
            *(uint4*)(&Bsm[br * LDA + bq * 32]) =
                make_uint4(pk[0], pk[1], pk[2], pk[3]);
            *(uint4*)(&Bsm[br * LDA + bq * 32 + 16]) =
                make_uint4(pk[4], pk[5], pk[6], pk[7]);
        }
        __syncthreads();
        if (kb < 10) loadAB(kb + 1);
        floatx4 cacc[16];
        #pragma unroll
        for (int i = 0; i < 16; i++) cacc[i] = fzero4();
        #pragma unroll
        for (int ks = 0; ks < 4; ks++) {
            long a[4], b[4];
            #pragma unroll
            for (int mi = 0; mi < 4; mi++)
                a[mi] = *(const long*)(&Asm[(wave * 64 + mi * 16 + lr) * LDA + ks * 32 + lq * 8]);
            #pragma unroll
            for (int ni = 0; ni < 4; ni++)
                b[ni] = *(const long*)(&Bsm[(ni * 16 + lr) * LDA + ks * 32 + lq * 8]);
            #pragma unroll
            for (int mi = 0; mi < 4; mi++)
                #pragma unroll
                for (int ni = 0; ni < 4; ni++)
                    cacc[mi * 4 + ni] = __builtin_amdgcn_mfma_f32_16x16x32_fp8_fp8(
                        a[mi], b[ni], cacc[mi * 4 + ni], 0, 0, 0);
        }
        float sw = sdp[kb];
        #pragma unroll
        for (int mi = 0; mi < 4; mi++) {
            #pragma unroll
            for (int reg = 0; reg < 4; reg++) {
                float sh = sha[(wave * 64 + mi * 16 + lq * 4 + reg) * 12 + kb];
                #pragma unroll
                for (int ni = 0; ni < 4; ni++)
                    facc[mi * 4 + ni][reg] += cacc[mi * 4 + ni][reg] * (sw * sh);
            }
        }
        __syncthreads();
    }

    #pragma unroll
    for (int mi = 0; mi < 4; mi++) {
        #pragma unroll
        for (int ni = 0; ni < 4; ni++) {
            #pragma unroll
            for (int reg = 0; reg < 4; reg++) {
                int r = wave * 64 + mi * 16 + lq * 4 + reg;
                if (r < rem) {
                    float v = facc[mi * 4 + ni][reg] * wgtL[r];
                    atomicAdd(out + (long)tokL[r] * HD + jb * 64 + ni * 16 + lr, v);
                }
            }
        }
    }
}

extern "C" void kernel_launch(void* const* d_in, const int* in_sizes, int n_in,
                              void* d_out, int out_size, void* d_ws, size_t ws_size,
                              hipStream_t stream) {
    (void)in_sizes; (void)n_in; (void)out_size;
    const float* x   = (const float*)d_in[0];
    const int*   tki = (const int*)d_in[1];
    const float* tkw = (const float*)d_in[2];
    const float* wgu = (const float*)d_in[3];
    const float* sgu = (const float*)d_in[4];
    const float* wd  = (const float*)d_in[5];
    const float* sd  = (const float*)d_in[6];
    float* out = (float*)d_out;
    char* ws = (char*)d_ws;

    int*   offs = (int*)(ws + OFF_OFFS);
    int*   tok  = (int*)(ws + OFF_TOK);
    float* wgt  = (float*)(ws + OFF_WGT);
    float* xs   = (float*)(ws + OFF_XS);
    unsigned char* xq = (unsigned char*)(ws + OFF_XQ);
    float* hs   = (float*)(ws + OFF_HS);
    unsigned char* hq = (unsigned char*)(ws + OFF_HQ);
    float* h32  = (float*)(ws + OFF_H32);
    unsigned char* wgu8 = (unsigned char*)(ws + OFF_WGU8);
    unsigned char* wd8  = (unsigned char*)(ws + OFF_WD8);

    bool big = ws_size >= WS_NEED;   // constant across calls -> same work each call

    hipMemsetAsync(d_out, 0, (size_t)NT * HD * sizeof(float), stream);
    route_kernel<<<1, 1024, 0, stream>>>(tki, tkw, offs, tok, wgt);
    quant_x_kernel<<<2048, 256, 0, stream>>>(x, xq, xs);
    if (big) {
        conv_w_kernel<<<4096, 256, 0, stream>>>(wgu, wd, wgu8, wd8);
        gemm1_kernel<1><<<dim3(44, 4, NE), 256, 0, stream>>>(xq, xs, wgu8, sgu, offs, tok, h32);
        quant_h_kernel<<<2816, 256, 0, stream>>>(h32, hq, hs);
        gemm2_kernel<1><<<dim3(32, 4, NE), 256, 0, stream>>>(hq, hs, wd8, sd, offs, tok, wgt, out);
    } else {
        gemm1_kernel<0><<<dim3(44, 4, NE), 256, 0, stream>>>(xq, xs, wgu, sgu, offs, tok, h32);
        quant_h_kernel<<<2816, 256, 0, stream>>>(h32, hq, hs);
        gemm2_kernel<0><<<dim3(32, 4, NE), 256, 0, stream>>>(hq, hs, wd, sd, offs, tok, wgt, out);
    }
}

// Round 4
// 477.643 us; speedup vs baseline: 1.1782x; 1.1782x over previous
//
#include <hip/hip_runtime.h>
#include <math.h>

#define NE 8
#define HD 2048
#define ID 1408
#define NT 512
#define FP8MAX 448.0f

typedef __attribute__((ext_vector_type(4))) float floatx4;

__device__ __forceinline__ floatx4 fzero4() {
    floatx4 z; z.x = 0.f; z.y = 0.f; z.z = 0.f; z.w = 0.f; return z;
}

// ---- ws layout (bytes) ----
#define OFF_OFFS  0                         // int[16]
#define OFF_TOK   1024                      // int[1024]
#define OFF_WGT   8192                      // float[1024]
#define OFF_ENT   16384                     // int[1024]  (slot -> entry)
#define OFF_XSG   32768                     // float[1024*16] entry-ordered x scales
#define OFF_XG    131072                    // u8[1024*2048] entry-ordered x codes (2 MB)
#define OFF_HS    (3*1024*1024)             // float[1024*11]
#define OFF_HQ    (3*1024*1024 + 65536)     // u8[1024*1408]
#define OFF_H32   (5*1024*1024)             // float[1024*1408] (5.77 MB)

#define LDA 136   // LDS row pitch for 128-byte fp8 rows (8-aligned; 4-way max conflicts)

// ---------------- routing ----------------
__global__ void route_kernel(const int* __restrict__ tki,
                             const float* __restrict__ tkw,
                             int* __restrict__ offs,
                             int* __restrict__ tok,
                             float* __restrict__ wgt,
                             int* __restrict__ ent) {
    __shared__ int cnt[NE];
    __shared__ int cur[NE];
    __shared__ int base[NE + 1];
    int tid = threadIdx.x;               // 1024 threads, one per (token, slot)
    if (tid < NE) { cnt[tid] = 0; cur[tid] = 0; }
    __syncthreads();
    int e = tki[tid];
    atomicAdd(&cnt[e], 1);
    __syncthreads();
    if (tid == 0) {
        int s = 0;
        for (int i = 0; i < NE; i++) { base[i] = s; s += cnt[i]; }
        base[NE] = s;
    }
    __syncthreads();
    int pos = atomicAdd(&cur[e], 1);
    int j = base[e] + pos;
    tok[j] = tid >> 1;                   // token id
    wgt[j] = tkw[tid];
    ent[tid] = j;                        // inverse map: (token,slot) -> entry
    if (tid <= NE) offs[tid] = base[tid];
}

// ---------------- x quantization + entry-ordered scatter ---------------------
__global__ void quant_x_kernel(const float* __restrict__ x,
                               const int* __restrict__ ent,
                               unsigned char* __restrict__ xg,
                               float* __restrict__ xsg) {
    int wid = (blockIdx.x * 256 + threadIdx.x) >> 6;   // 0..8191
    int lane = threadIdx.x & 63;
    int t = wid >> 4;
    int b = wid & 15;
    const float2 v = *(const float2*)(x + (long)t * HD + b * 128 + lane * 2);
    float am = fmaxf(fabsf(v.x), fabsf(v.y));
    #pragma unroll
    for (int m = 32; m; m >>= 1) am = fmaxf(am, __shfl_xor(am, m));
    float scale = fmaxf(am, 1e-12f) / FP8MAX;
    int p = __builtin_amdgcn_cvt_pk_fp8_f32(v.x / scale, v.y / scale, 0, false);
    unsigned short pk = (unsigned short)(p & 0xffff);
    int e0 = ent[2 * t], e1 = ent[2 * t + 1];
    *(unsigned short*)(xg + (long)e0 * HD + b * 128 + lane * 2) = pk;
    *(unsigned short*)(xg + (long)e1 * HD + b * 128 + lane * 2) = pk;
    if (lane == 0) { xsg[e0 * 16 + b] = scale; xsg[e1 * 16 + b] = scale; }
}

// ---------------- h quantization (entry-ordered already) ---------------------
__global__ void quant_h_kernel(const float* __restrict__ h32,
                               unsigned char* __restrict__ hq,
                               float* __restrict__ hs) {
    int wid = (blockIdx.x * 256 + threadIdx.x) >> 6;   // 0..11263
    int lane = threadIdx.x & 63;
    int j = wid / 11;
    int b = wid - j * 11;
    const float2 v = *(const float2*)(h32 + (long)j * ID + b * 128 + lane * 2);
    float am = fmaxf(fabsf(v.x), fabsf(v.y));
    #pragma unroll
    for (int m = 32; m; m >>= 1) am = fmaxf(am, __shfl_xor(am, m));
    float scale = fmaxf(am, 1e-12f) / FP8MAX;
    int p = __builtin_amdgcn_cvt_pk_fp8_f32(v.x / scale, v.y / scale, 0, false);
    *(unsigned short*)(hq + (long)j * ID + b * 128 + lane * 2) =
        (unsigned short)(p & 0xffff);
    if (lane == 0) hs[j * 11 + b] = scale;
}

// ---------------- gemm1: BM=128 x 32 gate/up col pairs, inline w-convert -----
__global__ __launch_bounds__(256) void gemm1_kernel(
    const unsigned char* __restrict__ xg,
    const float* __restrict__ xsg,
    const float* __restrict__ wgu,   // [E][2816][2048] fp32 codes
    const float* __restrict__ sgu,   // [E][22][16]
    const int* __restrict__ offs,
    float* __restrict__ h32) {
    int e = blockIdx.z;
    int mt = blockIdx.y;
    int jb = blockIdx.x;             // 0..43 (32 gate/up col pairs each)
    int o0 = offs[e], o1 = offs[e + 1];
    int ne = o1 - o0;
    int m0 = mt * 128;
    if (m0 >= ne) return;
    int rem = ne - m0;
    int j0 = o0 + m0;

    __shared__ __align__(16) unsigned char Asm[128 * LDA];  // 17408
    __shared__ __align__(16) unsigned char Bsm[64 * LDA];   // 8704
    __shared__ float sxa[128 * 20];                         // 10240

    int tid = threadIdx.x;
    {   // stage per-row x scales (2 threads/row)
        int r = tid >> 1, q = tid & 1;
        int j = j0 + r; if (j >= o1) j = o0;
        float4 s0 = *(const float4*)(xsg + j * 16 + q * 8);
        float4 s1 = *(const float4*)(xsg + j * 16 + q * 8 + 4);
        *(float4*)&sxa[r * 20 + q * 8] = s0;
        *(float4*)&sxa[r * 20 + q * 8 + 4] = s1;
    }

    int wave = tid >> 6;
    int lane = tid & 63;
    int lr = lane & 15;
    int lq = lane >> 4;

    // A staging: 4 steps x (8 threads/row, 16B each) — fully coalesced
    const unsigned char* aRow[4];
    int aseg = tid & 7;
    int arow[4];
    #pragma unroll
    for (int s = 0; s < 4; s++) {
        int r = s * 32 + (tid >> 3);
        arow[s] = r;
        int j = j0 + r; if (j >= o1) j = o0;
        aRow[s] = xg + (long)j * HD + aseg * 16;
    }

    int br = tid >> 2, bq = tid & 3;         // B: 64 rows, 32-float quarters
    long bn = (br < 32) ? (long)(jb * 32 + br)
                        : (long)(1408 + jb * 32 + (br - 32));
    const float* bptr = wgu + ((long)e * 2816 + bn) * HD;
    const float* sgp = sgu + (e * 22 + (jb >> 2)) * 16;
    const float* sup = sgu + (e * 22 + 11 + (jb >> 2)) * 16;

    floatx4 facc[8];
    #pragma unroll
    for (int i = 0; i < 8; i++) facc[i] = fzero4();

    uint4 aP[4];
    float4 bPf[8];
    auto loadAB = [&](int kb) {
        #pragma unroll
        for (int s = 0; s < 4; s++)
            aP[s] = *(const uint4*)(aRow[s] + kb * 128);
        const float4* bsrc = (const float4*)(bptr + kb * 128 + bq * 32);
        #pragma unroll
        for (int g = 0; g < 8; g++) bPf[g] = bsrc[g];
    };
    loadAB(0);

    for (int kb = 0; kb < 16; kb++) {
        #pragma unroll
        for (int s = 0; s < 4; s++)
            *(uint4*)(&Asm[arow[s] * LDA + aseg * 16]) = aP[s];
        {
            unsigned int pk[8];
            #pragma unroll
            for (int g = 0; g < 8; g++) {
                float4 f = bPf[g];
                int p = __builtin_amdgcn_cvt_pk_fp8_f32(f.x, f.y, 0, false);
                p = __builtin_amdgcn_cvt_pk_fp8_f32(f.z, f.w, p, true);
                pk[g] = (unsigned int)p;
            }
            *(uint4*)(&Bsm[br * LDA + bq * 32]) =
                make_uint4(pk[0], pk[1], pk[2], pk[3]);
            *(uint4*)(&Bsm[br * LDA + bq * 32 + 16]) =
                make_uint4(pk[4], pk[5], pk[6], pk[7]);
        }
        __syncthreads();
        if (kb < 15) loadAB(kb + 1);   // overlap next fetch with MFMA phase
        floatx4 cacc[8];
        #pragma unroll
        for (int i = 0; i < 8; i++) cacc[i] = fzero4();
        #pragma unroll
        for (int ks = 0; ks < 4; ks++) {
            long a[2], b[4];
            #pragma unroll
            for (int mi = 0; mi < 2; mi++)
                a[mi] = *(const long*)(&Asm[(wave * 32 + mi * 16 + lr) * LDA + ks * 32 + lq * 8]);
            #pragma unroll
            for (int ni = 0; ni < 4; ni++)
                b[ni] = *(const long*)(&Bsm[(ni * 16 + lr) * LDA + ks * 32 + lq * 8]);
            #pragma unroll
            for (int mi = 0; mi < 2; mi++)
                #pragma unroll
                for (int ni = 0; ni < 4; ni++)
                    cacc[mi * 4 + ni] = __builtin_amdgcn_mfma_f32_16x16x32_fp8_fp8(
                        a[mi], b[ni], cacc[mi * 4 + ni], 0, 0, 0);
        }
        float sg = sgp[kb];
        float su = sup[kb];
        #pragma unroll
        for (int mi = 0; mi < 2; mi++) {
            #pragma unroll
            for (int reg = 0; reg < 4; reg++) {
                float sx = sxa[(wave * 32 + mi * 16 + lq * 4 + reg) * 20 + kb];
                #pragma unroll
                for (int ni = 0; ni < 4; ni++) {
                    float sw = (ni < 2) ? sg : su;
                    facc[mi * 4 + ni][reg] += cacc[mi * 4 + ni][reg] * (sw * sx);
                }
            }
        }
        __syncthreads();
    }

    // epilogue: h = silu(gate) * up   (ni 0,1 = gate; ni 2,3 = matching up)
    #pragma unroll
    for (int mi = 0; mi < 2; mi++) {
        #pragma unroll
        for (int ni = 0; ni < 2; ni++) {
            #pragma unroll
            for (int reg = 0; reg < 4; reg++) {
                int r = wave * 32 + mi * 16 + lq * 4 + reg;
                if (r < rem) {
                    float g = facc[mi * 4 + ni][reg];
                    float u = facc[mi * 4 + ni + 2][reg];
                    float hval = (g / (1.0f + expf(-g))) * u;
                    h32[(long)(j0 + r) * ID + jb * 32 + ni * 16 + lr] = hval;
                }
            }
        }
    }
}

// ---------------- gemm2: BM=128 x BN=32 H-cols, weighted atomic scatter ------
__global__ __launch_bounds__(256) void gemm2_kernel(
    const unsigned char* __restrict__ hq,
    const float* __restrict__ hs,
    const float* __restrict__ wd,    // [E][2048][1408] fp32 codes
    const float* __restrict__ sd,    // [E][16][11]
    const int* __restrict__ offs,
    const int* __restrict__ tok,
    const float* __restrict__ wgt,
    float* __restrict__ out) {
    int e = blockIdx.z;
    int mt = blockIdx.y;
    int jb = blockIdx.x;             // 0..63 (32 H-cols each)
    int o0 = offs[e], o1 = offs[e + 1];
    int ne = o1 - o0;
    int m0 = mt * 128;
    if (m0 >= ne) return;
    int rem = ne - m0;
    int j0 = o0 + m0;

    __shared__ __align__(16) unsigned char Asm[128 * LDA];  // 17408
    __shared__ __align__(16) unsigned char Bsm[32 * LDA];   // 4352
    __shared__ float sha[128 * 12];                         // 6144
    __shared__ int tokL[128];
    __shared__ float wgtL[128];

    int tid = threadIdx.x;
    if (tid < 128) {
        int j = j0 + tid;
        int valid = j < o1;
        if (!valid) j = o0;
        tokL[tid] = tok[j];
        wgtL[tid] = valid ? wgt[j] : 0.0f;
        const float* s = hs + j * 11;
        #pragma unroll
        for (int k = 0; k < 11; k++) sha[tid * 12 + k] = s[k];
    }

    int wave = tid >> 6;
    int lane = tid & 63;
    int lr = lane & 15;
    int lq = lane >> 4;

    const unsigned char* aRow[4];
    int aseg = tid & 7;
    int arow[4];
    #pragma unroll
    for (int s = 0; s < 4; s++) {
        int r = s * 32 + (tid >> 3);
        arow[s] = r;
        int j = j0 + r; if (j >= o1) j = o0;
        aRow[s] = hq + (long)j * ID + aseg * 16;
    }

    int br = tid >> 3, bq = tid & 7;   // B: 32 rows, 16-float eighths
    const float* bptr = wd + ((long)e * HD + jb * 32 + br) * ID;
    const float* sdp = sd + (e * 16 + (jb >> 2)) * 11;

    floatx4 facc[4];
    #pragma unroll
    for (int i = 0; i < 4; i++) facc[i] = fzero4();

    uint4 aP[4];
    float4 bPf[4];
    auto loadAB = [&](int kb) {
        #pragma unroll
        for (int s = 0; s < 4; s++)
            aP[s] = *(const uint4*)(aRow[s] + kb * 128);
        const float4* bsrc = (const float4*)(bptr + kb * 128 + bq * 16);
        #pragma unroll
        for (int g = 0; g < 4; g++) bPf[g] = bsrc[g];
    };
    loadAB(0);

    for (int kb = 0; kb < 11; kb++) {
        #pragma unroll
        for (int s = 0; s < 4; s++)
            *(uint4*)(&Asm[arow[s] * LDA + aseg * 16]) = aP[s];
        {
            unsigned int pk[4];
            #pragma unroll
            for (int g = 0; g < 4; g++) {
                float4 f = bPf[g];
                int p = __builtin_amdgcn_cvt_pk_fp8_f32(f.x, f.y, 0, false);
                p = __builtin_amdgcn_cvt_pk_fp8_f32(f.z, f.w, p, true);
                pk[g] = (unsigned int)p;
            }
            *(uint4*)(&Bsm[br * LDA + bq * 16]) =
                make_uint4(pk[0], pk[1], pk[2], pk[3]);
        }
        __syncthreads();
        if (kb < 10) loadAB(kb + 1);
        floatx4 cacc[4];
        #pragma unroll
        for (int i = 0; i < 4; i++) cacc[i] = fzero4();
        #pragma unroll
        for (int ks = 0; ks < 4; ks++) {
            long a[2], b[2];
            #pragma unroll
            for (int mi = 0; mi < 2; mi++)
                a[mi] = *(const long*)(&Asm[(wave * 32 + mi * 16 + lr) * LDA + ks * 32 + lq * 8]);
            #pragma unroll
            for (int ni = 0; ni < 2; ni++)
                b[ni] = *(const long*)(&Bsm[(ni * 16 + lr) * LDA + ks * 32 + lq * 8]);
            #pragma unroll
            for (int mi = 0; mi < 2; mi++)
                #pragma unroll
                for (int ni = 0; ni < 2; ni++)
                    cacc[mi * 2 + ni] = __builtin_amdgcn_mfma_f32_16x16x32_fp8_fp8(
                        a[mi], b[ni], cacc[mi * 2 + ni], 0, 0, 0);
        }
        float sw = sdp[kb];
        #pragma unroll
        for (int mi = 0; mi < 2; mi++) {
            #pragma unroll
            for (int reg = 0; reg < 4; reg++) {
                float sh = sha[(wave * 32 + mi * 16 + lq * 4 + reg) * 12 + kb];
                #pragma unroll
                for (int ni = 0; ni < 2; ni++)
                    facc[mi * 2 + ni][reg] += cacc[mi * 2 + ni][reg] * (sw * sh);
            }
        }
        __syncthreads();
    }

    #pragma unroll
    for (int mi = 0; mi < 2; mi++) {
        #pragma unroll
        for (int ni = 0; ni < 2; ni++) {
            #pragma unroll
            for (int reg = 0; reg < 4; reg++) {
                int r = wave * 32 + mi * 16 + lq * 4 + reg;
                if (r < rem) {
                    float v = facc[mi * 2 + ni][reg] * wgtL[r];
                    atomicAdd(out + (long)tokL[r] * HD + jb * 32 + ni * 16 + lr, v);
                }
            }
        }
    }
}

extern "C" void kernel_launch(void* const* d_in, const int* in_sizes, int n_in,
                              void* d_out, int out_size, void* d_ws, size_t ws_size,
                              hipStream_t stream) {
    (void)in_sizes; (void)n_in; (void)out_size; (void)ws_size;
    const float* x   = (const float*)d_in[0];
    const int*   tki = (const int*)d_in[1];
    const float* tkw = (const float*)d_in[2];
    const float* wgu = (const float*)d_in[3];
    const float* sgu = (const float*)d_in[4];
    const float* wd  = (const float*)d_in[5];
    const float* sd  = (const float*)d_in[6];
    float* out = (float*)d_out;
    char* ws = (char*)d_ws;

    int*   offs = (int*)(ws + OFF_OFFS);
    int*   tok  = (int*)(ws + OFF_TOK);
    float* wgt  = (float*)(ws + OFF_WGT);
    int*   ent  = (int*)(ws + OFF_ENT);
    float* xsg  = (float*)(ws + OFF_XSG);
    unsigned char* xg = (unsigned char*)(ws + OFF_XG);
    float* hs   = (float*)(ws + OFF_HS);
    unsigned char* hq = (unsigned char*)(ws + OFF_HQ);
    float* h32  = (float*)(ws + OFF_H32);

    hipMemsetAsync(d_out, 0, (size_t)NT * HD * sizeof(float), stream);
    route_kernel<<<1, 1024, 0, stream>>>(tki, tkw, offs, tok, wgt, ent);
    quant_x_kernel<<<2048, 256, 0, stream>>>(x, ent, xg, xsg);
    gemm1_kernel<<<dim3(44, 8, NE), 256, 0, stream>>>(xg, xsg, wgu, sgu, offs, h32);
    quant_h_kernel<<<2816, 256, 0, stream>>>(h32, hq, hs);
    gemm2_kernel<<<dim3(64, 8, NE), 256, 0, stream>>>(hq, hs, wd, sd, offs, tok, wgt, out);
}

// Round 5
// 442.651 us; speedup vs baseline: 1.2714x; 1.0791x over previous
//
#include <hip/hip_runtime.h>
#include <math.h>

#define NE 8
#define HD 2048
#define ID 1408
#define NT 512
#define FP8MAX 448.0f

typedef __attribute__((ext_vector_type(4))) float floatx4;

__device__ __forceinline__ floatx4 fzero4() {
    floatx4 z; z.x = 0.f; z.y = 0.f; z.z = 0.f; z.w = 0.f; return z;
}

// ---- ws layout (bytes) ----
#define OFF_OFFS  0                         // int[16]
#define OFF_TOK   1024                      // int[1024]
#define OFF_WGT   8192                      // float[1024]
#define OFF_ENT   16384                     // int[1024]  (slot -> entry)
#define OFF_XSG   32768                     // float[1024*16] entry-ordered x scales
#define OFF_XG    131072                    // u8[1024*2048] entry-ordered x codes (2 MB)
#define OFF_HS    (3*1024*1024)             // float[1024*11]
#define OFF_HQ    (3*1024*1024 + 65536)     // u8[1024*1408]
#define OFF_H32   (5*1024*1024)             // float[1024*1408] (5.77 MB)

#define LDA 136   // LDS row pitch for 128-byte fp8 rows

// ---------------- routing ----------------
__global__ void route_kernel(const int* __restrict__ tki,
                             const float* __restrict__ tkw,
                             int* __restrict__ offs,
                             int* __restrict__ tok,
                             float* __restrict__ wgt,
                             int* __restrict__ ent) {
    __shared__ int cnt[NE];
    __shared__ int cur[NE];
    __shared__ int base[NE + 1];
    int tid = threadIdx.x;               // 1024 threads, one per (token, slot)
    if (tid < NE) { cnt[tid] = 0; cur[tid] = 0; }
    __syncthreads();
    int e = tki[tid];
    atomicAdd(&cnt[e], 1);
    __syncthreads();
    if (tid == 0) {
        int s = 0;
        for (int i = 0; i < NE; i++) { base[i] = s; s += cnt[i]; }
        base[NE] = s;
    }
    __syncthreads();
    int pos = atomicAdd(&cur[e], 1);
    int j = base[e] + pos;
    tok[j] = tid >> 1;                   // token id
    wgt[j] = tkw[tid];
    ent[tid] = j;                        // inverse map: (token,slot) -> entry
    if (tid <= NE) offs[tid] = base[tid];
}

// ---------------- x quantization + entry-ordered scatter ---------------------
__global__ void quant_x_kernel(const float* __restrict__ x,
                               const int* __restrict__ ent,
                               unsigned char* __restrict__ xg,
                               float* __restrict__ xsg) {
    int wid = (blockIdx.x * 256 + threadIdx.x) >> 6;   // 0..8191
    int lane = threadIdx.x & 63;
    int t = wid >> 4;
    int b = wid & 15;
    const float2 v = *(const float2*)(x + (long)t * HD + b * 128 + lane * 2);
    float am = fmaxf(fabsf(v.x), fabsf(v.y));
    #pragma unroll
    for (int m = 32; m; m >>= 1) am = fmaxf(am, __shfl_xor(am, m));
    float scale = fmaxf(am, 1e-12f) / FP8MAX;
    int p = __builtin_amdgcn_cvt_pk_fp8_f32(v.x / scale, v.y / scale, 0, false);
    unsigned short pk = (unsigned short)(p & 0xffff);
    int e0 = ent[2 * t], e1 = ent[2 * t + 1];
    *(unsigned short*)(xg + (long)e0 * HD + b * 128 + lane * 2) = pk;
    *(unsigned short*)(xg + (long)e1 * HD + b * 128 + lane * 2) = pk;
    if (lane == 0) { xsg[e0 * 16 + b] = scale; xsg[e1 * 16 + b] = scale; }
}

// ---------------- h quantization (entry-ordered already) ---------------------
__global__ void quant_h_kernel(const float* __restrict__ h32,
                               unsigned char* __restrict__ hq,
                               float* __restrict__ hs) {
    int wid = (blockIdx.x * 256 + threadIdx.x) >> 6;   // 0..11263
    int lane = threadIdx.x & 63;
    int j = wid / 11;
    int b = wid - j * 11;
    const float2 v = *(const float2*)(h32 + (long)j * ID + b * 128 + lane * 2);
    float am = fmaxf(fabsf(v.x), fabsf(v.y));
    #pragma unroll
    for (int m = 32; m; m >>= 1) am = fmaxf(am, __shfl_xor(am, m));
    float scale = fmaxf(am, 1e-12f) / FP8MAX;
    int p = __builtin_amdgcn_cvt_pk_fp8_f32(v.x / scale, v.y / scale, 0, false);
    *(unsigned short*)(hq + (long)j * ID + b * 128 + lane * 2) =
        (unsigned short)(p & 0xffff);
    if (lane == 0) hs[j * 11 + b] = scale;
}

// ---------------- gemm1: BM=128 x 32 gate/up col pairs, inline w-convert -----
// launch_bounds(256,2): 256-VGPR budget -> NO scratch spill (r4: 88 VGPR,
// spilled B prefetch, 87 MB scratch writes).
__global__ __launch_bounds__(256, 2) void gemm1_kernel(
    const unsigned char* __restrict__ xg,
    const float* __restrict__ xsg,
    const float* __restrict__ wgu,   // [E][2816][2048] fp32 codes
    const float* __restrict__ sgu,   // [E][22][16]
    const int* __restrict__ offs,
    float* __restrict__ h32) {
    int e = blockIdx.z;
    int mt = blockIdx.y;
    int jb = blockIdx.x;             // 0..43 (32 gate/up col pairs each)
    int o0 = offs[e], o1 = offs[e + 1];
    int ne = o1 - o0;
    int m0 = mt * 128;
    if (m0 >= ne) return;
    int rem = ne - m0;
    int j0 = o0 + m0;

    __shared__ __align__(16) unsigned char Asm[128 * LDA];  // 17408
    __shared__ __align__(16) unsigned char Bsm[64 * LDA];   // 8704
    __shared__ float sxa[128 * 20];                         // 10240

    int tid = threadIdx.x;
    {   // stage per-row x scales (2 threads/row)
        int r = tid >> 1, q = tid & 1;
        int j = j0 + r; if (j >= o1) j = o0;
        float4 s0 = *(const float4*)(xsg + j * 16 + q * 8);
        float4 s1 = *(const float4*)(xsg + j * 16 + q * 8 + 4);
        *(float4*)&sxa[r * 20 + q * 8] = s0;
        *(float4*)&sxa[r * 20 + q * 8 + 4] = s1;
    }

    int wave = tid >> 6;
    int lane = tid & 63;
    int lr = lane & 15;
    int lq = lane >> 4;

    // A staging: 4 steps x (8 threads/row, 16B each) — fully coalesced
    const unsigned char* aRow[4];
    int aseg = tid & 7;
    int arow[4];
    #pragma unroll
    for (int s = 0; s < 4; s++) {
        int r = s * 32 + (tid >> 3);
        arow[s] = r;
        int j = j0 + r; if (j >= o1) j = o0;
        aRow[s] = xg + (long)j * HD + aseg * 16;
    }

    // B staging: coalesced — 32 consecutive lanes cover one row's 512B chunk.
    int bcol = tid & 31;             // float4 index (16B) within 128-float chunk
    int brow0 = tid >> 5;            // 0..7
    const float* bRow[8];
    #pragma unroll
    for (int g = 0; g < 8; g++) {
        int row = g * 8 + brow0;     // 0..63
        long bn = (row < 32) ? (long)(jb * 32 + row)
                             : (long)(1408 + jb * 32 + (row - 32));
        bRow[g] = wgu + ((long)e * 2816 + bn) * HD + bcol * 4;
    }
    const float* sgp = sgu + (e * 22 + (jb >> 2)) * 16;
    const float* sup = sgu + (e * 22 + 11 + (jb >> 2)) * 16;

    floatx4 facc[8];
    #pragma unroll
    for (int i = 0; i < 8; i++) facc[i] = fzero4();

    uint4 aP[4];
    float4 bPf[8];
    auto loadAB = [&](int kb) {
        #pragma unroll
        for (int s = 0; s < 4; s++)
            aP[s] = *(const uint4*)(aRow[s] + kb * 128);
        #pragma unroll
        for (int g = 0; g < 8; g++)
            bPf[g] = *(const float4*)(bRow[g] + kb * 128);
    };
    loadAB(0);

    for (int kb = 0; kb < 16; kb++) {
        #pragma unroll
        for (int s = 0; s < 4; s++)
            *(uint4*)(&Asm[arow[s] * LDA + aseg * 16]) = aP[s];
        #pragma unroll
        for (int g = 0; g < 8; g++) {
            float4 f = bPf[g];
            int p = __builtin_amdgcn_cvt_pk_fp8_f32(f.x, f.y, 0, false);
            p = __builtin_amdgcn_cvt_pk_fp8_f32(f.z, f.w, p, true);
            *(unsigned int*)(&Bsm[(g * 8 + brow0) * LDA + bcol * 4]) = (unsigned int)p;
        }
        __syncthreads();
        if (kb < 15) loadAB(kb + 1);   // overlap next fetch with MFMA phase
        floatx4 cacc[8];
        #pragma unroll
        for (int i = 0; i < 8; i++) cacc[i] = fzero4();
        #pragma unroll
        for (int ks = 0; ks < 4; ks++) {
            long a[2], b[4];
            #pragma unroll
            for (int mi = 0; mi < 2; mi++)
                a[mi] = *(const long*)(&Asm[(wave * 32 + mi * 16 + lr) * LDA + ks * 32 + lq * 8]);
            #pragma unroll
            for (int ni = 0; ni < 4; ni++)
                b[ni] = *(const long*)(&Bsm[(ni * 16 + lr) * LDA + ks * 32 + lq * 8]);
            #pragma unroll
            for (int mi = 0; mi < 2; mi++)
                #pragma unroll
                for (int ni = 0; ni < 4; ni++)
                    cacc[mi * 4 + ni] = __builtin_amdgcn_mfma_f32_16x16x32_fp8_fp8(
                        a[mi], b[ni], cacc[mi * 4 + ni], 0, 0, 0);
        }
        float sg = sgp[kb];
        float su = sup[kb];
        #pragma unroll
        for (int mi = 0; mi < 2; mi++) {
            #pragma unroll
            for (int reg = 0; reg < 4; reg++) {
                float sx = sxa[(wave * 32 + mi * 16 + lq * 4 + reg) * 20 + kb];
                #pragma unroll
                for (int ni = 0; ni < 4; ni++) {
                    float sw = (ni < 2) ? sg : su;
                    facc[mi * 4 + ni][reg] += cacc[mi * 4 + ni][reg] * (sw * sx);
                }
            }
        }
        __syncthreads();
    }

    // epilogue: h = silu(gate) * up   (ni 0,1 = gate; ni 2,3 = matching up)
    #pragma unroll
    for (int mi = 0; mi < 2; mi++) {
        #pragma unroll
        for (int ni = 0; ni < 2; ni++) {
            #pragma unroll
            for (int reg = 0; reg < 4; reg++) {
                int r = wave * 32 + mi * 16 + lq * 4 + reg;
                if (r < rem) {
                    float g = facc[mi * 4 + ni][reg];
                    float u = facc[mi * 4 + ni + 2][reg];
                    float hval = (g / (1.0f + expf(-g))) * u;
                    h32[(long)(j0 + r) * ID + jb * 32 + ni * 16 + lr] = hval;
                }
            }
        }
    }
}

// ---------------- gemm2: BM=128 x BN=32 H-cols, weighted atomic scatter ------
__global__ __launch_bounds__(256, 2) void gemm2_kernel(
    const unsigned char* __restrict__ hq,
    const float* __restrict__ hs,
    const float* __restrict__ wd,    // [E][2048][1408] fp32 codes
    const float* __restrict__ sd,    // [E][16][11]
    const int* __restrict__ offs,
    const int* __restrict__ tok,
    const float* __restrict__ wgt,
    float* __restrict__ out) {
    int e = blockIdx.z;
    int mt = blockIdx.y;
    int jb = blockIdx.x;             // 0..63 (32 H-cols each)
    int o0 = offs[e], o1 = offs[e + 1];
    int ne = o1 - o0;
    int m0 = mt * 128;
    if (m0 >= ne) return;
    int rem = ne - m0;
    int j0 = o0 + m0;

    __shared__ __align__(16) unsigned char Asm[128 * LDA];  // 17408
    __shared__ __align__(16) unsigned char Bsm[32 * LDA];   // 4352
    __shared__ float sha[128 * 12];                         // 6144
    __shared__ int tokL[128];
    __shared__ float wgtL[128];

    int tid = threadIdx.x;
    if (tid < 128) {
        int j = j0 + tid;
        int valid = j < o1;
        if (!valid) j = o0;
        tokL[tid] = tok[j];
        wgtL[tid] = valid ? wgt[j] : 0.0f;
        const float* s = hs + j * 11;
        #pragma unroll
        for (int k = 0; k < 11; k++) sha[tid * 12 + k] = s[k];
    }

    int wave = tid >> 6;
    int lane = tid & 63;
    int lr = lane & 15;
    int lq = lane >> 4;

    const unsigned char* aRow[4];
    int aseg = tid & 7;
    int arow[4];
    #pragma unroll
    for (int s = 0; s < 4; s++) {
        int r = s * 32 + (tid >> 3);
        arow[s] = r;
        int j = j0 + r; if (j >= o1) j = o0;
        aRow[s] = hq + (long)j * ID + aseg * 16;
    }

    // B staging: coalesced — 32 lanes cover one row's 512B chunk
    int bcol = tid & 31;
    int brow0 = tid >> 5;            // 0..7
    const float* bRow[4];
    #pragma unroll
    for (int g = 0; g < 4; g++) {
        int row = g * 8 + brow0;     // 0..31
        bRow[g] = wd + ((long)e * HD + jb * 32 + row) * ID + bcol * 4;
    }
    const float* sdp = sd + (e * 16 + (jb >> 2)) * 11;

    floatx4 facc[4];
    #pragma unroll
    for (int i = 0; i < 4; i++) facc[i] = fzero4();

    uint4 aP[4];
    float4 bPf[4];
    auto loadAB = [&](int kb) {
        #pragma unroll
        for (int s = 0; s < 4; s++)
            aP[s] = *(const uint4*)(aRow[s] + kb * 128);
        #pragma unroll
        for (int g = 0; g < 4; g++)
            bPf[g] = *(const float4*)(bRow[g] + kb * 128);
    };
    loadAB(0);

    for (int kb = 0; kb < 11; kb++) {
        #pragma unroll
        for (int s = 0; s < 4; s++)
            *(uint4*)(&Asm[arow[s] * LDA + aseg * 16]) = aP[s];
        #pragma unroll
        for (int g = 0; g < 4; g++) {
            float4 f = bPf[g];
            int p = __builtin_amdgcn_cvt_pk_fp8_f32(f.x, f.y, 0, false);
            p = __builtin_amdgcn_cvt_pk_fp8_f32(f.z, f.w, p, true);
            *(unsigned int*)(&Bsm[(g * 8 + brow0) * LDA + bcol * 4]) = (unsigned int)p;
        }
        __syncthreads();
        if (kb < 10) loadAB(kb + 1);
        floatx4 cacc[4];
        #pragma unroll
        for (int i = 0; i < 4; i++) cacc[i] = fzero4();
        #pragma unroll
        for (int ks = 0; ks < 4; ks++) {
            long a[2], b[2];
            #pragma unroll
            for (int mi = 0; mi < 2; mi++)
                a[mi] = *(const long*)(&Asm[(wave * 32 + mi * 16 + lr) * LDA + ks * 32 + lq * 8]);
            #pragma unroll
            for (int ni = 0; ni < 2; ni++)
                b[ni] = *(const long*)(&Bsm[(ni * 16 + lr) * LDA + ks * 32 + lq * 8]);
            #pragma unroll
            for (int mi = 0; mi < 2; mi++)
                #pragma unroll
                for (int ni = 0; ni < 2; ni++)
                    cacc[mi * 2 + ni] = __builtin_amdgcn_mfma_f32_16x16x32_fp8_fp8(
                        a[mi], b[ni], cacc[mi * 2 + ni], 0, 0, 0);
        }
        float sw = sdp[kb];
        #pragma unroll
        for (int mi = 0; mi < 2; mi++) {
            #pragma unroll
            for (int reg = 0; reg < 4; reg++) {
                float sh = sha[(wave * 32 + mi * 16 + lq * 4 + reg) * 12 + kb];
                #pragma unroll
                for (int ni = 0; ni < 2; ni++)
                    facc[mi * 2 + ni][reg] += cacc[mi * 2 + ni][reg] * (sw * sh);
            }
        }
        __syncthreads();
    }

    #pragma unroll
    for (int mi = 0; mi < 2; mi++) {
        #pragma unroll
        for (int ni = 0; ni < 2; ni++) {
            #pragma unroll
            for (int reg = 0; reg < 4; reg++) {
                int r = wave * 32 + mi * 16 + lq * 4 + reg;
                if (r < rem) {
                    float v = facc[mi * 2 + ni][reg] * wgtL[r];
                    atomicAdd(out + (long)tokL[r] * HD + jb * 32 + ni * 16 + lr, v);
                }
            }
        }
    }
}

extern "C" void kernel_launch(void* const* d_in, const int* in_sizes, int n_in,
                              void* d_out, int out_size, void* d_ws, size_t ws_size,
                              hipStream_t stream) {
    (void)in_sizes; (void)n_in; (void)out_size; (void)ws_size;
    const float* x   = (const float*)d_in[0];
    const int*   tki = (const int*)d_in[1];
    const float* tkw = (const float*)d_in[2];
    const float* wgu = (const float*)d_in[3];
    const float* sgu = (const float*)d_in[4];
    const float* wd  = (const float*)d_in[5];
    const float* sd  = (const float*)d_in[6];
    float* out = (float*)d_out;
    char* ws = (char*)d_ws;

    int*   offs = (int*)(ws + OFF_OFFS);
    int*   tok  = (int*)(ws + OFF_TOK);
    float* wgt  = (float*)(ws + OFF_WGT);
    int*   ent  = (int*)(ws + OFF_ENT);
    float* xsg  = (float*)(ws + OFF_XSG);
    unsigned char* xg = (unsigned char*)(ws + OFF_XG);
    float* hs   = (float*)(ws + OFF_HS);
    unsigned char* hq = (unsigned char*)(ws + OFF_HQ);
    float* h32  = (float*)(ws + OFF_H32);

    hipMemsetAsync(d_out, 0, (size_t)NT * HD * sizeof(float), stream);
    route_kernel<<<1, 1024, 0, stream>>>(tki, tkw, offs, tok, wgt, ent);
    quant_x_kernel<<<2048, 256, 0, stream>>>(x, ent, xg, xsg);
    gemm1_kernel<<<dim3(44, 8, NE), 256, 0, stream>>>(xg, xsg, wgu, sgu, offs, h32);
    quant_h_kernel<<<2816, 256, 0, stream>>>(h32, hq, hs);
    gemm2_kernel<<<dim3(64, 8, NE), 256, 0, stream>>>(hq, hs, wd, sd, offs, tok, wgt, out);
}

// Round 6
// 380.999 us; speedup vs baseline: 1.4771x; 1.1618x over previous
//
#include <hip/hip_runtime.h>
#include <math.h>

#define NE 8
#define HD 2048
#define ID 1408
#define NT 512
#define FP8MAX 448.0f

typedef __attribute__((ext_vector_type(4))) float floatx4;

__device__ __forceinline__ floatx4 fzero4() {
    floatx4 z; z.x = 0.f; z.y = 0.f; z.z = 0.f; z.w = 0.f; return z;
}

// ---- ws layout (bytes) ----
#define OFF_OFFS  0                         // int[16]
#define OFF_TOK   1024                      // int[1024]
#define OFF_WGT   8192                      // float[1024]
#define OFF_ENT   16384                     // int[1024]  (slot -> entry)
#define OFF_XSG   32768                     // float[1024*16] entry-ordered x scales
#define OFF_XG    131072                    // u8[1024*2048] entry-ordered x codes (2 MB)
#define OFF_HS    (3*1024*1024)             // float[1024*11]
#define OFF_HQ    (3*1024*1024 + 65536)     // u8[1024*1408]
#define OFF_H32   (5*1024*1024)             // float[1024*1408] (5.77 MB)

#define LDA 136   // LDS row pitch for 128-byte fp8 rows

// ---------------- routing ----------------
__global__ void route_kernel(const int* __restrict__ tki,
                             const float* __restrict__ tkw,
                             int* __restrict__ offs,
                             int* __restrict__ tok,
                             float* __restrict__ wgt,
                             int* __restrict__ ent) {
    __shared__ int cnt[NE];
    __shared__ int cur[NE];
    __shared__ int base[NE + 1];
    int tid = threadIdx.x;               // 1024 threads, one per (token, slot)
    if (tid < NE) { cnt[tid] = 0; cur[tid] = 0; }
    __syncthreads();
    int e = tki[tid];
    atomicAdd(&cnt[e], 1);
    __syncthreads();
    if (tid == 0) {
        int s = 0;
        for (int i = 0; i < NE; i++) { base[i] = s; s += cnt[i]; }
        base[NE] = s;
    }
    __syncthreads();
    int pos = atomicAdd(&cur[e], 1);
    int j = base[e] + pos;
    tok[j] = tid >> 1;                   // token id
    wgt[j] = tkw[tid];
    ent[tid] = j;                        // inverse map: (token,slot) -> entry
    if (tid <= NE) offs[tid] = base[tid];
}

// ---------------- x quantization + entry-ordered scatter ---------------------
__global__ void quant_x_kernel(const float* __restrict__ x,
                               const int* __restrict__ ent,
                               unsigned char* __restrict__ xg,
                               float* __restrict__ xsg) {
    int wid = (blockIdx.x * 256 + threadIdx.x) >> 6;   // 0..8191
    int lane = threadIdx.x & 63;
    int t = wid >> 4;
    int b = wid & 15;
    const float2 v = *(const float2*)(x + (long)t * HD + b * 128 + lane * 2);
    float am = fmaxf(fabsf(v.x), fabsf(v.y));
    #pragma unroll
    for (int m = 32; m; m >>= 1) am = fmaxf(am, __shfl_xor(am, m));
    float scale = fmaxf(am, 1e-12f) / FP8MAX;
    int p = __builtin_amdgcn_cvt_pk_fp8_f32(v.x / scale, v.y / scale, 0, false);
    unsigned short pk = (unsigned short)(p & 0xffff);
    int e0 = ent[2 * t], e1 = ent[2 * t + 1];
    *(unsigned short*)(xg + (long)e0 * HD + b * 128 + lane * 2) = pk;
    *(unsigned short*)(xg + (long)e1 * HD + b * 128 + lane * 2) = pk;
    if (lane == 0) { xsg[e0 * 16 + b] = scale; xsg[e1 * 16 + b] = scale; }
}

// ---------------- h quantization (entry-ordered already) ---------------------
__global__ void quant_h_kernel(const float* __restrict__ h32,
                               unsigned char* __restrict__ hq,
                               float* __restrict__ hs) {
    int wid = (blockIdx.x * 256 + threadIdx.x) >> 6;   // 0..11263
    int lane = threadIdx.x & 63;
    int j = wid / 11;
    int b = wid - j * 11;
    const float2 v = *(const float2*)(h32 + (long)j * ID + b * 128 + lane * 2);
    float am = fmaxf(fabsf(v.x), fabsf(v.y));
    #pragma unroll
    for (int m = 32; m; m >>= 1) am = fmaxf(am, __shfl_xor(am, m));
    float scale = fmaxf(am, 1e-12f) / FP8MAX;
    int p = __builtin_amdgcn_cvt_pk_fp8_f32(v.x / scale, v.y / scale, 0, false);
    *(unsigned short*)(hq + (long)j * ID + b * 128 + lane * 2) =
        (unsigned short)(p & 0xffff);
    if (lane == 0) hs[j * 11 + b] = scale;
}

// ---------------- gemm1: BM=128 x 32 gate/up col pairs, inline w-convert -----
// NO software prefetch: loads are transient within the staging phase so no
// values live across the barrier/MFMA phase (r4/r5 spilled the prefetch:
// 75-87 MB scratch writes). Latency hiding comes from 3+ blocks/CU.
__global__ __launch_bounds__(256, 3) void gemm1_kernel(
    const unsigned char* __restrict__ xg,
    const float* __restrict__ xsg,
    const float* __restrict__ wgu,   // [E][2816][2048] fp32 codes
    const float* __restrict__ sgu,   // [E][22][16]
    const int* __restrict__ offs,
    float* __restrict__ h32) {
    int e = blockIdx.z;
    int mt = blockIdx.y;
    int jb = blockIdx.x;             // 0..43 (32 gate/up col pairs each)
    int o0 = offs[e], o1 = offs[e + 1];
    int ne = o1 - o0;
    int m0 = mt * 128;
    if (m0 >= ne) return;
    int rem = ne - m0;
    int j0 = o0 + m0;

    __shared__ __align__(16) unsigned char Asm[128 * LDA];  // 17408
    __shared__ __align__(16) unsigned char Bsm[64 * LDA];   // 8704
    __shared__ float sxa[128 * 20];                         // 10240

    int tid = threadIdx.x;
    {   // stage per-row x scales (2 threads/row)
        int r = tid >> 1, q = tid & 1;
        int j = j0 + r; if (j >= o1) j = o0;
        float4 s0 = *(const float4*)(xsg + j * 16 + q * 8);
        float4 s1 = *(const float4*)(xsg + j * 16 + q * 8 + 4);
        *(float4*)&sxa[r * 20 + q * 8] = s0;
        *(float4*)&sxa[r * 20 + q * 8 + 4] = s1;
    }

    int wave = tid >> 6;
    int lane = tid & 63;
    int lr = lane & 15;
    int lq = lane >> 4;

    // A staging: 4 steps x (8 threads/row, 16B each) — fully coalesced
    int aseg = tid & 7;
    int arow0 = tid >> 3;            // 0..31
    const unsigned char* aBase0;
    const unsigned char* aBase1;
    const unsigned char* aBase2;
    const unsigned char* aBase3;
    {
        int j;
        j = j0 + arow0;       if (j >= o1) j = o0; aBase0 = xg + (long)j * HD + aseg * 16;
        j = j0 + 32 + arow0;  if (j >= o1) j = o0; aBase1 = xg + (long)j * HD + aseg * 16;
        j = j0 + 64 + arow0;  if (j >= o1) j = o0; aBase2 = xg + (long)j * HD + aseg * 16;
        j = j0 + 96 + arow0;  if (j >= o1) j = o0; aBase3 = xg + (long)j * HD + aseg * 16;
    }

    // B staging: coalesced — 32 consecutive lanes cover one row's 512B chunk.
    int bcol = tid & 31;             // float4 (16B) index within 128-float chunk
    int brow0 = tid >> 5;            // 0..7
    const float* bG = wgu + ((long)e * 2816 + jb * 32 + brow0) * HD + bcol * 4;
    const float* bU = wgu + ((long)e * 2816 + 1408 + jb * 32 + brow0) * HD + bcol * 4;
    const float* sgp = sgu + (e * 22 + (jb >> 2)) * 16;
    const float* sup = sgu + (e * 22 + 11 + (jb >> 2)) * 16;

    floatx4 facc[8];
    #pragma unroll
    for (int i = 0; i < 8; i++) facc[i] = fzero4();

    for (int kb = 0; kb < 16; kb++) {
        // ---- staging phase (all values transient) ----
        {
            uint4 a0 = *(const uint4*)(aBase0 + kb * 128);
            uint4 a1 = *(const uint4*)(aBase1 + kb * 128);
            uint4 a2 = *(const uint4*)(aBase2 + kb * 128);
            uint4 a3 = *(const uint4*)(aBase3 + kb * 128);
            float4 f0 = *(const float4*)(bG + kb * 128);
            float4 f1 = *(const float4*)(bG + kb * 128 + 8 * HD);
            float4 f2 = *(const float4*)(bG + kb * 128 + 16 * HD);
            float4 f3 = *(const float4*)(bG + kb * 128 + 24 * HD);
            float4 f4 = *(const float4*)(bU + kb * 128);
            float4 f5 = *(const float4*)(bU + kb * 128 + 8 * HD);
            float4 f6 = *(const float4*)(bU + kb * 128 + 16 * HD);
            float4 f7 = *(const float4*)(bU + kb * 128 + 24 * HD);
            *(uint4*)(&Asm[(arow0)      * LDA + aseg * 16]) = a0;
            *(uint4*)(&Asm[(arow0 + 32) * LDA + aseg * 16]) = a1;
            *(uint4*)(&Asm[(arow0 + 64) * LDA + aseg * 16]) = a2;
            *(uint4*)(&Asm[(arow0 + 96) * LDA + aseg * 16]) = a3;
            int p0 = __builtin_amdgcn_cvt_pk_fp8_f32(f0.x, f0.y, 0, false);
            p0 = __builtin_amdgcn_cvt_pk_fp8_f32(f0.z, f0.w, p0, true);
            int p1 = __builtin_amdgcn_cvt_pk_fp8_f32(f1.x, f1.y, 0, false);
            p1 = __builtin_amdgcn_cvt_pk_fp8_f32(f1.z, f1.w, p1, true);
            int p2 = __builtin_amdgcn_cvt_pk_fp8_f32(f2.x, f2.y, 0, false);
            p2 = __builtin_amdgcn_cvt_pk_fp8_f32(f2.z, f2.w, p2, true);
            int p3 = __builtin_amdgcn_cvt_pk_fp8_f32(f3.x, f3.y, 0, false);
            p3 = __builtin_amdgcn_cvt_pk_fp8_f32(f3.z, f3.w, p3, true);
            int p4 = __builtin_amdgcn_cvt_pk_fp8_f32(f4.x, f4.y, 0, false);
            p4 = __builtin_amdgcn_cvt_pk_fp8_f32(f4.z, f4.w, p4, true);
            int p5 = __builtin_amdgcn_cvt_pk_fp8_f32(f5.x, f5.y, 0, false);
            p5 = __builtin_amdgcn_cvt_pk_fp8_f32(f5.z, f5.w, p5, true);
            int p6 = __builtin_amdgcn_cvt_pk_fp8_f32(f6.x, f6.y, 0, false);
            p6 = __builtin_amdgcn_cvt_pk_fp8_f32(f6.z, f6.w, p6, true);
            int p7 = __builtin_amdgcn_cvt_pk_fp8_f32(f7.x, f7.y, 0, false);
            p7 = __builtin_amdgcn_cvt_pk_fp8_f32(f7.z, f7.w, p7, true);
            *(unsigned int*)(&Bsm[(brow0)      * LDA + bcol * 4]) = (unsigned int)p0;
            *(unsigned int*)(&Bsm[(brow0 + 8)  * LDA + bcol * 4]) = (unsigned int)p1;
            *(unsigned int*)(&Bsm[(brow0 + 16) * LDA + bcol * 4]) = (unsigned int)p2;
            *(unsigned int*)(&Bsm[(brow0 + 24) * LDA + bcol * 4]) = (unsigned int)p3;
            *(unsigned int*)(&Bsm[(brow0 + 32) * LDA + bcol * 4]) = (unsigned int)p4;
            *(unsigned int*)(&Bsm[(brow0 + 40) * LDA + bcol * 4]) = (unsigned int)p5;
            *(unsigned int*)(&Bsm[(brow0 + 48) * LDA + bcol * 4]) = (unsigned int)p6;
            *(unsigned int*)(&Bsm[(brow0 + 56) * LDA + bcol * 4]) = (unsigned int)p7;
        }
        __syncthreads();
        // ---- MFMA phase ----
        floatx4 cacc[8];
        #pragma unroll
        for (int i = 0; i < 8; i++) cacc[i] = fzero4();
        #pragma unroll
        for (int ks = 0; ks < 4; ks++) {
            long a[2], b[4];
            #pragma unroll
            for (int mi = 0; mi < 2; mi++)
                a[mi] = *(const long*)(&Asm[(wave * 32 + mi * 16 + lr) * LDA + ks * 32 + lq * 8]);
            #pragma unroll
            for (int ni = 0; ni < 4; ni++)
                b[ni] = *(const long*)(&Bsm[(ni * 16 + lr) * LDA + ks * 32 + lq * 8]);
            #pragma unroll
            for (int mi = 0; mi < 2; mi++)
                #pragma unroll
                for (int ni = 0; ni < 4; ni++)
                    cacc[mi * 4 + ni] = __builtin_amdgcn_mfma_f32_16x16x32_fp8_fp8(
                        a[mi], b[ni], cacc[mi * 4 + ni], 0, 0, 0);
        }
        float sg = sgp[kb];
        float su = sup[kb];
        #pragma unroll
        for (int mi = 0; mi < 2; mi++) {
            #pragma unroll
            for (int reg = 0; reg < 4; reg++) {
                float sx = sxa[(wave * 32 + mi * 16 + lq * 4 + reg) * 20 + kb];
                #pragma unroll
                for (int ni = 0; ni < 4; ni++) {
                    float sw = (ni < 2) ? sg : su;
                    facc[mi * 4 + ni][reg] += cacc[mi * 4 + ni][reg] * (sw * sx);
                }
            }
        }
        __syncthreads();
    }

    // epilogue: h = silu(gate) * up   (ni 0,1 = gate; ni 2,3 = matching up)
    #pragma unroll
    for (int mi = 0; mi < 2; mi++) {
        #pragma unroll
        for (int ni = 0; ni < 2; ni++) {
            #pragma unroll
            for (int reg = 0; reg < 4; reg++) {
                int r = wave * 32 + mi * 16 + lq * 4 + reg;
                if (r < rem) {
                    float g = facc[mi * 4 + ni][reg];
                    float u = facc[mi * 4 + ni + 2][reg];
                    float hval = (g / (1.0f + expf(-g))) * u;
                    h32[(long)(j0 + r) * ID + jb * 32 + ni * 16 + lr] = hval;
                }
            }
        }
    }
}

// ---------------- gemm2: BM=128 x BN=32 H-cols, weighted atomic scatter ------
__global__ __launch_bounds__(256, 4) void gemm2_kernel(
    const unsigned char* __restrict__ hq,
    const float* __restrict__ hs,
    const float* __restrict__ wd,    // [E][2048][1408] fp32 codes
    const float* __restrict__ sd,    // [E][16][11]
    const int* __restrict__ offs,
    const int* __restrict__ tok,
    const float* __restrict__ wgt,
    float* __restrict__ out) {
    int e = blockIdx.z;
    int mt = blockIdx.y;
    int jb = blockIdx.x;             // 0..63 (32 H-cols each)
    int o0 = offs[e], o1 = offs[e + 1];
    int ne = o1 - o0;
    int m0 = mt * 128;
    if (m0 >= ne) return;
    int rem = ne - m0;
    int j0 = o0 + m0;

    __shared__ __align__(16) unsigned char Asm[128 * LDA];  // 17408
    __shared__ __align__(16) unsigned char Bsm[32 * LDA];   // 4352
    __shared__ float sha[128 * 12];                         // 6144
    __shared__ int tokL[128];
    __shared__ float wgtL[128];

    int tid = threadIdx.x;
    if (tid < 128) {
        int j = j0 + tid;
        int valid = j < o1;
        if (!valid) j = o0;
        tokL[tid] = tok[j];
        wgtL[tid] = valid ? wgt[j] : 0.0f;
        const float* s = hs + j * 11;
        #pragma unroll
        for (int k = 0; k < 11; k++) sha[tid * 12 + k] = s[k];
    }

    int wave = tid >> 6;
    int lane = tid & 63;
    int lr = lane & 15;
    int lq = lane >> 4;

    int aseg = tid & 7;
    int arow0 = tid >> 3;            // 0..31
    const unsigned char* aBase0;
    const unsigned char* aBase1;
    const unsigned char* aBase2;
    const unsigned char* aBase3;
    {
        int j;
        j = j0 + arow0;       if (j >= o1) j = o0; aBase0 = hq + (long)j * ID + aseg * 16;
        j = j0 + 32 + arow0;  if (j >= o1) j = o0; aBase1 = hq + (long)j * ID + aseg * 16;
        j = j0 + 64 + arow0;  if (j >= o1) j = o0; aBase2 = hq + (long)j * ID + aseg * 16;
        j = j0 + 96 + arow0;  if (j >= o1) j = o0; aBase3 = hq + (long)j * ID + aseg * 16;
    }

    // B staging: coalesced — 32 lanes cover one row's 512B chunk
    int bcol = tid & 31;
    int brow0 = tid >> 5;            // 0..7
    const float* bB = wd + ((long)e * HD + jb * 32 + brow0) * ID + bcol * 4;
    const float* sdp = sd + (e * 16 + (jb >> 2)) * 11;

    floatx4 facc[4];
    #pragma unroll
    for (int i = 0; i < 4; i++) facc[i] = fzero4();

    for (int kb = 0; kb < 11; kb++) {
        {
            uint4 a0 = *(const uint4*)(aBase0 + kb * 128);
            uint4 a1 = *(const uint4*)(aBase1 + kb * 128);
            uint4 a2 = *(const uint4*)(aBase2 + kb * 128);
            uint4 a3 = *(const uint4*)(aBase3 + kb * 128);
            float4 f0 = *(const float4*)(bB + kb * 128);
            float4 f1 = *(const float4*)(bB + kb * 128 + 8 * ID);
            float4 f2 = *(const float4*)(bB + kb * 128 + 16 * ID);
            float4 f3 = *(const float4*)(bB + kb * 128 + 24 * ID);
            *(uint4*)(&Asm[(arow0)      * LDA + aseg * 16]) = a0;
            *(uint4*)(&Asm[(arow0 + 32) * LDA + aseg * 16]) = a1;
            *(uint4*)(&Asm[(arow0 + 64) * LDA + aseg * 16]) = a2;
            *(uint4*)(&Asm[(arow0 + 96) * LDA + aseg * 16]) = a3;
            int p0 = __builtin_amdgcn_cvt_pk_fp8_f32(f0.x, f0.y, 0, false);
            p0 = __builtin_amdgcn_cvt_pk_fp8_f32(f0.z, f0.w, p0, true);
            int p1 = __builtin_amdgcn_cvt_pk_fp8_f32(f1.x, f1.y, 0, false);
            p1 = __builtin_amdgcn_cvt_pk_fp8_f32(f1.z, f1.w, p1, true);
            int p2 = __builtin_amdgcn_cvt_pk_fp8_f32(f2.x, f2.y, 0, false);
            p2 = __builtin_amdgcn_cvt_pk_fp8_f32(f2.z, f2.w, p2, true);
            int p3 = __builtin_amdgcn_cvt_pk_fp8_f32(f3.x, f3.y, 0, false);
            p3 = __builtin_amdgcn_cvt_pk_fp8_f32(f3.z, f3.w, p3, true);
            *(unsigned int*)(&Bsm[(brow0)      * LDA + bcol * 4]) = (unsigned int)p0;
            *(unsigned int*)(&Bsm[(brow0 + 8)  * LDA + bcol * 4]) = (unsigned int)p1;
            *(unsigned int*)(&Bsm[(brow0 + 16) * LDA + bcol * 4]) = (unsigned int)p2;
            *(unsigned int*)(&Bsm[(brow0 + 24) * LDA + bcol * 4]) = (unsigned int)p3;
        }
        __syncthreads();
        floatx4 cacc[4];
        #pragma unroll
        for (int i = 0; i < 4; i++) cacc[i] = fzero4();
        #pragma unroll
        for (int ks = 0; ks < 4; ks++) {
            long a[2], b[2];
            #pragma unroll
            for (int mi = 0; mi < 2; mi++)
                a[mi] = *(const long*)(&Asm[(wave * 32 + mi * 16 + lr) * LDA + ks * 32 + lq * 8]);
            #pragma unroll
            for (int ni = 0; ni < 2; ni++)
                b[ni] = *(const long*)(&Bsm[(ni * 16 + lr) * LDA + ks * 32 + lq * 8]);
            #pragma unroll
            for (int mi = 0; mi < 2; mi++)
                #pragma unroll
                for (int ni = 0; ni < 2; ni++)
                    cacc[mi * 2 + ni] = __builtin_amdgcn_mfma_f32_16x16x32_fp8_fp8(
                        a[mi], b[ni], cacc[mi * 2 + ni], 0, 0, 0);
        }
        float sw = sdp[kb];
        #pragma unroll
        for (int mi = 0; mi < 2; mi++) {
            #pragma unroll
            for (int reg = 0; reg < 4; reg++) {
                float sh = sha[(wave * 32 + mi * 16 + lq * 4 + reg) * 12 + kb];
                #pragma unroll
                for (int ni = 0; ni < 2; ni++)
                    facc[mi * 2 + ni][reg] += cacc[mi * 2 + ni][reg] * (sw * sh);
            }
        }
        __syncthreads();
    }

    #pragma unroll
    for (int mi = 0; mi < 2; mi++) {
        #pragma unroll
        for (int ni = 0; ni < 2; ni++) {
            #pragma unroll
            for (int reg = 0; reg < 4; reg++) {
                int r = wave * 32 + mi * 16 + lq * 4 + reg;
                if (r < rem) {
                    float v = facc[mi * 2 + ni][reg] * wgtL[r];
                    atomicAdd(out + (long)tokL[r] * HD + jb * 32 + ni * 16 + lr, v);
                }
            }
        }
    }
}

extern "C" void kernel_launch(void* const* d_in, const int* in_sizes, int n_in,
                              void* d_out, int out_size, void* d_ws, size_t ws_size,
                              hipStream_t stream) {
    (void)in_sizes; (void)n_in; (void)out_size; (void)ws_size;
    const float* x   = (const float*)d_in[0];
    const int*   tki = (const int*)d_in[1];
    const float* tkw = (const float*)d_in[2];
    const float* wgu = (const float*)d_in[3];
    const float* sgu = (const float*)d_in[4];
    const float* wd  = (const float*)d_in[5];
    const float* sd  = (const float*)d_in[6];
    float* out = (float*)d_out;
    char* ws = (char*)d_ws;

    int*   offs = (int*)(ws + OFF_OFFS);
    int*   tok  = (int*)(ws + OFF_TOK);
    float* wgt  = (float*)(ws + OFF_WGT);
    int*   ent  = (int*)(ws + OFF_ENT);
    float* xsg  = (float*)(ws + OFF_XSG);
    unsigned char* xg = (unsigned char*)(ws + OFF_XG);
    float* hs   = (float*)(ws + OFF_HS);
    unsigned char* hq = (unsigned char*)(ws + OFF_HQ);
    float* h32  = (float*)(ws + OFF_H32);

    hipMemsetAsync(d_out, 0, (size_t)NT * HD * sizeof(float), stream);
    route_kernel<<<1, 1024, 0, stream>>>(tki, tkw, offs, tok, wgt, ent);
    quant_x_kernel<<<2048, 256, 0, stream>>>(x, ent, xg, xsg);
    gemm1_kernel<<<dim3(44, 8, NE), 256, 0, stream>>>(xg, xsg, wgu, sgu, offs, h32);
    quant_h_kernel<<<2816, 256, 0, stream>>>(h32, hq, hs);
    gemm2_kernel<<<dim3(64, 8, NE), 256, 0, stream>>>(hq, hs, wd, sd, offs, tok, wgt, out);
}